// Round 8
// baseline (715.391 us; speedup 1.0000x reference)
//
#include <hip/hip_runtime.h>
#include <hip/hip_bf16.h>

#define N_NODES 100000
#define N_EDGES 1600000
#define D_NODE 128
#define D_EDGE 64
#define D_MSG 128
#define K1 192   // NODE_DIM + EDGE_DIM
#define K2 256   // NODE_DIM + MSG_DIM
#define D_OUT 128
#define NSB 98   // scan blocks: ceil(100000/1024)
#define TILE 64
#define NT (N_EDGES / TILE)   // 25000 exact

using frag8 = __attribute__((ext_vector_type(8))) short;   // 8 bf16 (4 VGPRs)
using facc  = __attribute__((ext_vector_type(4))) float;   // 4 f32 acc

static __device__ __forceinline__ unsigned short f2bf(float f) {
    unsigned int u = __float_as_uint(f);
    u = u + 0x7fffu + ((u >> 16) & 1u);   // RNE
    return (unsigned short)(u >> 16);
}
static __device__ __forceinline__ float bflo(unsigned int u) { return __uint_as_float(u << 16); }
static __device__ __forceinline__ float bfhi(unsigned int u) { return __uint_as_float(u & 0xffff0000u); }

union F8 { unsigned short s[8]; frag8 f; uint4 u4; };

static __device__ __forceinline__ frag8 pack8(float4 a, float4 b) {
    F8 u;
    u.s[0] = f2bf(a.x); u.s[1] = f2bf(a.y); u.s[2] = f2bf(a.z); u.s[3] = f2bf(a.w);
    u.s[4] = f2bf(b.x); u.s[5] = f2bf(b.y); u.s[6] = f2bf(b.z); u.s[7] = f2bf(b.w);
    return u.f;
}

// ---------------------------------------------------------------------------
// prep_all: W transpose->bf16, node_emb->bf16, dst histogram. One launch.
// ---------------------------------------------------------------------------
__global__ void prep_all_kernel(const float* __restrict__ Wm, const float* __restrict__ Wu,
                                const float* __restrict__ node_emb, const int* __restrict__ dst,
                                unsigned short* __restrict__ WtM, unsigned short* __restrict__ WtU,
                                unsigned int* __restrict__ nodeB32, int* __restrict__ cnt) {
    int idx0 = blockIdx.x * blockDim.x + threadIdx.x;
    int stride = gridDim.x * blockDim.x;
    for (int idx = idx0; idx < 128 * K1; idx += stride) {
        int o = idx / K1, k = idx - o * K1;
        WtM[idx] = f2bf(Wm[k * D_MSG + o]);
    }
    for (int idx = idx0; idx < 128 * K2; idx += stride) {
        int o = idx >> 8, k = idx & 255;
        WtU[idx] = f2bf(Wu[k * D_OUT + o]);
    }
    const int total = N_NODES * 64;   // u32 pairs
    for (int i = idx0; i < total; i += stride) {
        float2 v = *(const float2*)&node_emb[(size_t)i * 2];
        nodeB32[i] = (unsigned)f2bf(v.x) | ((unsigned)f2bf(v.y) << 16);
    }
    for (int e = idx0; e < N_EDGES; e += stride) {
        int d = min(max(dst[e], 0), N_NODES - 1);
        atomicAdd(&cnt[d], 1);
    }
}

__global__ __launch_bounds__(1024) void scan_blocks(const int* __restrict__ cnt,
                                                    int* __restrict__ base,
                                                    int* __restrict__ part) {
    __shared__ int sh[1024];
    int i = blockIdx.x * 1024 + threadIdx.x;
    int c = (i < N_NODES) ? cnt[i] : 0;
    sh[threadIdx.x] = c;
    __syncthreads();
    for (int s = 1; s < 1024; s <<= 1) {
        int t = (threadIdx.x >= s) ? sh[threadIdx.x - s] : 0;
        __syncthreads();
        sh[threadIdx.x] += t;
        __syncthreads();
    }
    if (i < N_NODES) base[i] = sh[threadIdx.x] - c;   // exclusive within block
    if (threadIdx.x == 1023) part[blockIdx.x] = sh[1023];
}

__global__ __launch_bounds__(128) void scan_partials(int* __restrict__ part) {
    __shared__ int sh[128];
    int i = threadIdx.x;
    int c = (i < NSB) ? part[i] : 0;
    sh[i] = c;
    __syncthreads();
    for (int s = 1; s < 128; s <<= 1) {
        int t = (i >= s) ? sh[i - s] : 0;
        __syncthreads();
        sh[i] += t;
        __syncthreads();
    }
    if (i < NSB) part[i] = sh[i] - c;   // exclusive
}

__global__ __launch_bounds__(1024) void scan_add(int* __restrict__ base, const int* __restrict__ part) {
    int i = blockIdx.x * 1024 + threadIdx.x;
    if (i < N_NODES) base[i] += part[blockIdx.x];
}

// ---------------------------------------------------------------------------
// scatter2: bin edges by dst; emit srcS, dstS AND permuted bf16 edge rows.
// Sequential edge_emb read; random (but 128B-contiguous) edgeB writes.
// ---------------------------------------------------------------------------
__global__ void scatter2_kernel(const int* __restrict__ dst, const int* __restrict__ src,
                                const float* __restrict__ edge_emb,
                                const int* __restrict__ base, int* __restrict__ cursor,
                                int* __restrict__ srcS, int* __restrict__ dstS,
                                unsigned short* __restrict__ edgeB) {
    int idx0 = blockIdx.x * blockDim.x + threadIdx.x;
    int stride = gridDim.x * blockDim.x;
    for (int e = idx0; e < N_EDGES; e += stride) {
        int d = min(max(dst[e], 0), N_NODES - 1);
        int pos = base[d] + atomicAdd(&cursor[d], 1);
        srcS[pos] = src[e];
        dstS[pos] = d;
        const float* er = edge_emb + (size_t)e * D_EDGE;
        unsigned short* ob = edgeB + (size_t)pos * D_EDGE;
#pragma unroll
        for (int c = 0; c < 4; ++c) {
            float4 a = *(const float4*)&er[c * 16 + 0];
            float4 b = *(const float4*)&er[c * 16 + 4];
            float4 g = *(const float4*)&er[c * 16 + 8];
            float4 h = *(const float4*)&er[c * 16 + 12];
            F8 u0; u0.f = pack8(a, b);
            F8 u1; u1.f = pack8(g, h);
            // FIX (round-7 bug): 16 floats -> 16 contiguous bf16 ELEMENTS
            *(uint4*)&ob[c * 16 + 0] = u0.u4;
            *(uint4*)&ob[c * 16 + 8] = u1.u4;
        }
    }
}

// ---------------------------------------------------------------------------
// FUSED Phase A: per 64-edge tile: msg GEMM (W in regs, inputs staged in
// XOR-swizzled LDS; edge rows read SEQUENTIALLY as bf16) -> msg tile in LDS
// -> in-block per-node mean. Interior nodes: direct mean row write.
// Non-interior: plain f32 spill row (NO atomics); cleanup kernel finishes.
// ---------------------------------------------------------------------------
__global__ __launch_bounds__(256, 4) void msg_fused_kernel(
    const unsigned short* __restrict__ nodeB, const int* __restrict__ srcS,
    const int* __restrict__ dstS, const unsigned short* __restrict__ edgeB,
    const unsigned short* __restrict__ WtM, const float* __restrict__ b_msg,
    const int* __restrict__ base, const int* __restrict__ cnt,
    float* __restrict__ mean, float* __restrict__ spill)
{
    __shared__ unsigned short sIn[TILE][192];    // 24576 B; 16B chunks XOR row&7
    __shared__ unsigned short sMsg[TILE][128];   // 16384 B; 8B chunks XOR row&7

    const int lane = threadIdx.x & 63;
    const int wav  = threadIdx.x >> 6;
    const int j = lane & 15;
    const int q = lane >> 4;

    // W slice (out rows 32*wav .. 32*wav+31) in registers
    frag8 wfr[2][6];
#pragma unroll
    for (int m2 = 0; m2 < 2; ++m2) {
        const unsigned short* wrow = WtM + ((wav * 2 + m2) * 16 + j) * K1;
#pragma unroll
        for (int kc = 0; kc < 6; ++kc)
            wfr[m2][kc] = *(const frag8*)&wrow[(kc * 4 + q) * 8];
    }
    float bias[2][4];
#pragma unroll
    for (int m2 = 0; m2 < 2; ++m2)
#pragma unroll
        for (int r = 0; r < 4; ++r) bias[m2][r] = b_msg[(wav * 2 + m2) * 16 + q * 4 + r];

    // staging role: thread t covers edge row eL = t>>2, quarter qt = t&3
    const int eL = threadIdx.x >> 2;
    const int qt = threadIdx.x & 3;
    const int swz = eL & 7;

    uint4 nst[4];   // node part: 64B bf16
    uint4 est[2];   // edge part: 32B bf16 (pre-converted, sequential)

    const int t0 = blockIdx.x;

    // prologue: issue loads for tile t0
    {
        const int e = t0 * TILE + eL;
        const int sp = min(max(srcS[e], 0), N_NODES - 1);
        const unsigned short* nrow = nodeB + (size_t)sp * D_NODE + qt * 32;
#pragma unroll
        for (int i = 0; i < 4; ++i) nst[i] = *(const uint4*)&nrow[i * 8];
        const unsigned short* erow = edgeB + (size_t)e * D_EDGE + qt * 16;
        est[0] = *(const uint4*)&erow[0];
        est[1] = *(const uint4*)&erow[8];
    }

#pragma unroll 1
    for (int t = t0; t < NT; t += gridDim.x) {
        const int e0 = t * TILE;

        __syncthreads();   // (a) prior GEMM + reduction done; sIn free

        // write staged tile into sIn (XOR-swizzled 16B chunks)
        {
            unsigned short* drow = &sIn[eL][0];
#pragma unroll
            for (int i = 0; i < 4; ++i)
                *(uint4*)&drow[((4 * qt + i) ^ swz) * 8] = nst[i];
#pragma unroll
            for (int h = 0; h < 2; ++h)
                *(uint4*)&drow[((16 + 2 * qt + h) ^ swz) * 8] = est[h];
        }
        __syncthreads();   // (b) sIn ready

        // issue next tile's loads early (latency hides under compute)
        const int tn = t + gridDim.x;
        if (tn < NT) {
            const int e = tn * TILE + eL;
            const int sp = min(max(srcS[e], 0), N_NODES - 1);
            const unsigned short* nrow = nodeB + (size_t)sp * D_NODE + qt * 32;
#pragma unroll
            for (int i = 0; i < 4; ++i) nst[i] = *(const uint4*)&nrow[i * 8];
            const unsigned short* erow = edgeB + (size_t)e * D_EDGE + qt * 16;
            est[0] = *(const uint4*)&erow[0];
            est[1] = *(const uint4*)&erow[8];
        }

        // GEMM: wave computes outs 32*wav..+31 for all 64 edges
        facc acc[2][4];
#pragma unroll
        for (int m2 = 0; m2 < 2; ++m2)
#pragma unroll
            for (int eg = 0; eg < 4; ++eg) { facc z = {0.f,0.f,0.f,0.f}; acc[m2][eg] = z; }

        const int rsw = j & 7;
#pragma unroll
        for (int eg = 0; eg < 4; ++eg) {
            const unsigned short* irow = &sIn[eg * 16 + j][0];
#pragma unroll
            for (int kc = 0; kc < 6; ++kc) {
                frag8 b = *(const frag8*)&irow[((4 * kc + q) ^ rsw) * 8];
                acc[0][eg] = __builtin_amdgcn_mfma_f32_16x16x32_bf16(wfr[0][kc], b, acc[0][eg], 0, 0, 0);
                acc[1][eg] = __builtin_amdgcn_mfma_f32_16x16x32_bf16(wfr[1][kc], b, acc[1][eg], 0, 0, 0);
            }
        }

        // epilogue: bias+relu+cvt bf16 -> sMsg (8B chunks XOR row&7)
#pragma unroll
        for (int eg = 0; eg < 4; ++eg) {
            unsigned short* mrow = &sMsg[eg * 16 + j][0];
#pragma unroll
            for (int m2 = 0; m2 < 2; ++m2) {
                float v0 = fmaxf(acc[m2][eg][0] + bias[m2][0], 0.f);
                float v1 = fmaxf(acc[m2][eg][1] + bias[m2][1], 0.f);
                float v2 = fmaxf(acc[m2][eg][2] + bias[m2][2], 0.f);
                float v3 = fmaxf(acc[m2][eg][3] + bias[m2][3], 0.f);
                uint2 w;
                w.x = (unsigned)f2bf(v0) | ((unsigned)f2bf(v1) << 16);
                w.y = (unsigned)f2bf(v2) | ((unsigned)f2bf(v3) << 16);
                int c64 = wav * 8 + m2 * 4 + q;        // u64 index 0..31
                *(uint2*)&mrow[(c64 ^ rsw) * 4] = w;
            }
        }
        __syncthreads();   // (c) sMsg ready

        // in-block mean finish: wave handles nodes d_lo+wav, +4, ...
        const int d_lo = dstS[e0];
        const int d_hi = dstS[e0 + TILE - 1];
        for (int n = d_lo + wav; n <= d_hi; n += 4) {
            const int b = base[n];
            const int c = cnt[n];
            const int lo = max(b - e0, 0);
            const int hi = min(b + c - e0, TILE);
            float s0 = 0.f, s1 = 0.f;
            for (int r = lo; r < hi; ++r) {
                const unsigned* mr = (const unsigned*)&sMsg[r][0];
                unsigned u = mr[(((lane >> 1) ^ (r & 7)) << 1) | (lane & 1)];
                s0 += bflo(u); s1 += bfhi(u);
            }
            const float inv = 1.0f / fmaxf((float)c, 1.0f);
            s0 *= inv; s1 *= inv;
            if (b >= e0 && b + c <= e0 + TILE) {
                // interior: exclusive owner, direct mean row write
                *(float2*)(mean + (size_t)n * D_MSG + lane * 2) = make_float2(s0, s1);
            } else {
                // non-interior: deterministic spill slot (NO atomics)
                int slot = (n == d_lo) ? 0 : 1;
                *(float2*)(spill + ((size_t)(t * 2 + slot)) * D_MSG + lane * 2) = make_float2(s0, s1);
            }
        }
    }
}

// ---------------------------------------------------------------------------
// cleanup: finish boundary nodes (sum their per-tile spill rows) and write
// zero rows for degree-0 nodes. Interior nodes were written by msg_fused.
// ---------------------------------------------------------------------------
__global__ __launch_bounds__(256) void cleanup_kernel(
    const int* __restrict__ dstS, const int* __restrict__ base,
    const int* __restrict__ cnt, const float* __restrict__ spill,
    float* __restrict__ mean)
{
    const int wav = threadIdx.x >> 6;
    const int lane = threadIdx.x & 63;
    const int n = blockIdx.x * 4 + wav;
    const int c = cnt[n];
    float s0 = 0.f, s1 = 0.f;
    if (c > 0) {
        const int b = base[n];
        const int t0 = b >> 6, t1 = (b + c - 1) >> 6;
        if (t0 == t1) return;   // interior: already written by msg_fused
        for (int t = t0; t <= t1; ++t) {
            const int slot = (dstS[t * TILE] == n) ? 0 : 1;
            const float* sp = spill + ((size_t)(t * 2 + slot)) * D_MSG + lane * 2;
            s0 += sp[0]; s1 += sp[1];
        }
    }
    *(float2*)(mean + (size_t)n * D_MSG + lane * 2) = make_float2(s0, s1);
}

// ---------------------------------------------------------------------------
// Phase C: node GEMM. nodeB bf16 fragments + mean f32 (packed on the fly).
// ---------------------------------------------------------------------------
__global__ __launch_bounds__(256) void node_gemm_kernel(
    const unsigned short* __restrict__ nodeB, const float* __restrict__ mean,
    const unsigned short* __restrict__ WtU, const float* __restrict__ b_upd,
    float* __restrict__ out)
{
    __shared__ unsigned short sW[128 * K2];   // 65536 B

    for (int idx = threadIdx.x; idx < 128 * 32; idx += 256) {
        int o = idx >> 5, ch = idx & 31;
        *(uint4*)&sW[o * K2 + (ch ^ (o & 7)) * 8] = *(const uint4*)&WtU[o * K2 + ch * 8];
    }

    const int lane = threadIdx.x & 63;
    const int wav  = threadIdx.x >> 6;
    const int j = lane & 15;
    const int q = lane >> 4;
    const int rs = j & 7;

    float bias[32];
#pragma unroll
    for (int mt = 0; mt < 8; ++mt)
#pragma unroll
        for (int r = 0; r < 4; ++r) bias[mt * 4 + r] = b_upd[mt * 16 + q * 4 + r];
    __syncthreads();

    const int n0w = blockIdx.x * 256 + wav * 64;

#pragma unroll 1
    for (int g = 0; g < 4; ++g) {
        const int n = n0w + g * 16 + j;
        const bool valid = (n < N_NODES);
        const size_t nn = valid ? (size_t)n : 0;

        frag8 bfr[8];
        const unsigned short* nrow = nodeB + nn * D_NODE;
#pragma unroll
        for (int kc = 0; kc < 4; ++kc)
            bfr[kc] = *(const frag8*)&nrow[kc * 32 + q * 8];
        const float* mrow = mean + nn * D_MSG;
#pragma unroll
        for (int kc = 0; kc < 4; ++kc) {
            float4 a = *(const float4*)&mrow[kc * 32 + q * 8];
            float4 c = *(const float4*)&mrow[kc * 32 + q * 8 + 4];
            bfr[4 + kc] = pack8(a, c);
        }

        facc acc[8];
#pragma unroll
        for (int mt = 0; mt < 8; ++mt) { facc z = {0.f, 0.f, 0.f, 0.f}; acc[mt] = z; }

#pragma unroll
        for (int mt = 0; mt < 8; ++mt) {
            const unsigned short* wrow = &sW[(mt * 16 + j) * K2];
#pragma unroll
            for (int kc = 0; kc < 8; ++kc) {
                frag8 a = *(const frag8*)&wrow[((kc * 4 + q) ^ rs) * 8];
                acc[mt] = __builtin_amdgcn_mfma_f32_16x16x32_bf16(a, bfr[kc], acc[mt], 0, 0, 0);
            }
        }

        if (valid) {
            float* orow = out + (size_t)n * D_OUT;
#pragma unroll
            for (int mt = 0; mt < 8; ++mt)
#pragma unroll
                for (int r = 0; r < 4; ++r)
                    orow[mt * 16 + q * 4 + r] = fmaxf(acc[mt][r] + bias[mt * 4 + r], 0.f);
        }
    }
}

// ===========================================================================
// FALLBACK PATH (round-3): fused msg+aggregate if ws too small.
// ===========================================================================
__global__ void prep_w_kernel(const float* __restrict__ Wm, const float* __restrict__ Wu,
                              unsigned short* __restrict__ WtM, unsigned short* __restrict__ WtU) {
    int idx0 = blockIdx.x * blockDim.x + threadIdx.x;
    int stride = gridDim.x * blockDim.x;
    for (int idx = idx0; idx < 128 * K1; idx += stride) {
        int o = idx / K1, k = idx - o * K1;
        WtM[idx] = f2bf(Wm[k * D_MSG + o]);
    }
    for (int idx = idx0; idx < 128 * K2; idx += stride) {
        int o = idx >> 8, k = idx & 255;
        WtU[idx] = f2bf(Wu[k * D_OUT + o]);
    }
}

__global__ void hist_kernel(const int* __restrict__ dst, int* __restrict__ cnt) {
    int idx0 = blockIdx.x * blockDim.x + threadIdx.x;
    int stride = gridDim.x * blockDim.x;
    for (int e = idx0; e < N_EDGES; e += stride) {
        int d = min(max(dst[e], 0), N_NODES - 1);
        atomicAdd(&cnt[d], 1);
    }
}

__global__ void scatter_kernel(const int* __restrict__ dst, const int* __restrict__ src,
                               const int* __restrict__ base, int* __restrict__ cursor,
                               int* __restrict__ perm, int* __restrict__ srcS,
                               int* __restrict__ dstS) {
    int idx0 = blockIdx.x * blockDim.x + threadIdx.x;
    int stride = gridDim.x * blockDim.x;
    for (int e = idx0; e < N_EDGES; e += stride) {
        int d = min(max(dst[e], 0), N_NODES - 1);
        int pos = base[d] + atomicAdd(&cursor[d], 1);
        perm[pos] = e;
        srcS[pos] = src[e];
        dstS[pos] = d;
    }
}

__global__ __launch_bounds__(256) void msg_agg_kernel_fb(
    const float* __restrict__ node_emb, const int* __restrict__ src,
    const float* __restrict__ edge_emb, const unsigned short* __restrict__ WtM,
    const float* __restrict__ b_msg, const int* __restrict__ perm,
    const int* __restrict__ dstS, const int* __restrict__ cnt,
    float* __restrict__ mean)
{
    __shared__ unsigned short sW[128 * K1];

    for (int idx = threadIdx.x; idx < 128 * 24; idx += 256) {
        int o = idx / 24, ch = idx % 24;
        *(uint4*)&sW[o * K1 + (ch ^ (o & 7)) * 8] = *(const uint4*)&WtM[o * K1 + ch * 8];
    }

    const int lane = threadIdx.x & 63;
    const int wav  = threadIdx.x >> 6;
    const int j = lane & 15;
    const int q = lane >> 4;

    float bias[32];
#pragma unroll
    for (int mt = 0; mt < 8; ++mt)
#pragma unroll
        for (int r = 0; r < 4; ++r) bias[mt * 4 + r] = b_msg[mt * 16 + q * 4 + r];
    __syncthreads();

    const int e0w = blockIdx.x * 256 + wav * 64;
    float carry[32];
    int carry_d = -1;

#pragma unroll 1
    for (int g = 0; g < 4; ++g) {
        const int e = e0w + g * 16 + j;
        const int p = perm[e];
        const int d = dstS[e];
        const int sp = min(max(src[p], 0), N_NODES - 1);
        const float invc = 1.0f / (float)cnt[d];

        frag8 bfr[6];
        const float* nrow = node_emb + (size_t)sp * D_NODE;
#pragma unroll
        for (int kc = 0; kc < 4; ++kc) {
            float4 a = *(const float4*)&nrow[kc * 32 + q * 8];
            float4 c = *(const float4*)&nrow[kc * 32 + q * 8 + 4];
            bfr[kc] = pack8(a, c);
        }
        const float* erow = edge_emb + (size_t)p * D_EDGE;
#pragma unroll
        for (int kc = 0; kc < 2; ++kc) {
            float4 a = *(const float4*)&erow[kc * 32 + q * 8];
            float4 c = *(const float4*)&erow[kc * 32 + q * 8 + 4];
            bfr[4 + kc] = pack8(a, c);
        }

        facc acc[8];
#pragma unroll
        for (int mt = 0; mt < 8; ++mt) { facc z = {0.f, 0.f, 0.f, 0.f}; acc[mt] = z; }

#pragma unroll
        for (int mt = 0; mt < 8; ++mt) {
            const unsigned short* wrow = &sW[(mt * 16 + j) * K1];
            const int rs = j & 7;
#pragma unroll
            for (int kc = 0; kc < 6; ++kc) {
                frag8 a = *(const frag8*)&wrow[((kc * 4 + q) ^ rs) * 8];
                acc[mt] = __builtin_amdgcn_mfma_f32_16x16x32_bf16(a, bfr[kc], acc[mt], 0, 0, 0);
            }
        }

        float v[32];
#pragma unroll
        for (int mt = 0; mt < 8; ++mt)
#pragma unroll
            for (int r = 0; r < 4; ++r) {
                float t = acc[mt][r] + bias[mt * 4 + r];
                v[mt * 4 + r] = fmaxf(t, 0.f) * invc;
            }

        int dprev = __shfl_up(d, 1, 16);
        int head = (j == 0 || d != dprev) ? 1 : 0;
        int seg = head;
#pragma unroll
        for (int s = 1; s < 16; s <<= 1) { int t = __shfl_up(seg, s, 16); if (j >= s) seg += t; }
        int sg1 = __shfl_up(seg, 1, 16);
        int sg2 = __shfl_up(seg, 2, 16);
        int sg4 = __shfl_up(seg, 4, 16);
        int sg8 = __shfl_up(seg, 8, 16);
        bool ok1 = (j >= 1) && (sg1 == seg);
        bool ok2 = (j >= 2) && (sg2 == seg);
        bool ok4 = (j >= 4) && (sg4 == seg);
        bool ok8 = (j >= 8) && (sg8 == seg);

#pragma unroll
        for (int i = 0; i < 32; ++i) { float t = __shfl_up(v[i], 1, 16); if (ok1) v[i] += t; }
#pragma unroll
        for (int i = 0; i < 32; ++i) { float t = __shfl_up(v[i], 2, 16); if (ok2) v[i] += t; }
#pragma unroll
        for (int i = 0; i < 32; ++i) { float t = __shfl_up(v[i], 4, 16); if (ok4) v[i] += t; }
#pragma unroll
        for (int i = 0; i < 32; ++i) { float t = __shfl_up(v[i], 8, 16); if (ok8) v[i] += t; }

        int d0 = __shfl(d, 0, 16);
        if (g > 0) {
            if (d0 != carry_d) {
                if (j == 0) {
                    float* mrow = mean + (size_t)carry_d * D_MSG;
#pragma unroll
                    for (int mt = 0; mt < 8; ++mt)
#pragma unroll
                        for (int r = 0; r < 4; ++r)
                            atomicAdd(&mrow[mt * 16 + q * 4 + r], carry[mt * 4 + r]);
                }
            } else if (seg == 1) {
#pragma unroll
                for (int i = 0; i < 32; ++i) v[i] += carry[i];
            }
        }

#pragma unroll
        for (int i = 0; i < 32; ++i) carry[i] = __shfl(v[i], 15, 16);
        carry_d = __shfl(d, 15, 16);

        int dnext = __shfl_down(d, 1, 16);
        bool tail = (j < 15) ? (dnext != d) : (g == 3);
        if (tail) {
            float* mrow = mean + (size_t)d * D_MSG;
#pragma unroll
            for (int mt = 0; mt < 8; ++mt)
#pragma unroll
                for (int r = 0; r < 4; ++r)
                    atomicAdd(&mrow[mt * 16 + q * 4 + r], v[mt * 4 + r]);
        }
    }
}

__global__ __launch_bounds__(256) void node_kernel_fb(
    const float* __restrict__ node_emb, const float* __restrict__ mean,
    const unsigned short* __restrict__ WtU, const float* __restrict__ b_upd,
    float* __restrict__ out)
{
    __shared__ unsigned short sW[128 * K2];

    for (int idx = threadIdx.x; idx < 128 * 32; idx += 256) {
        int o = idx >> 5, ch = idx & 31;
        *(uint4*)&sW[o * K2 + (ch ^ (o & 7)) * 8] = *(const uint4*)&WtU[o * K2 + ch * 8];
    }

    const int lane = threadIdx.x & 63;
    const int wav  = threadIdx.x >> 6;
    const int j = lane & 15;
    const int q = lane >> 4;

    float bias[32];
#pragma unroll
    for (int mt = 0; mt < 8; ++mt)
#pragma unroll
        for (int r = 0; r < 4; ++r) bias[mt * 4 + r] = b_upd[mt * 16 + q * 4 + r];
    __syncthreads();

    const int n0w = blockIdx.x * 256 + wav * 64;

#pragma unroll 1
    for (int g = 0; g < 4; ++g) {
        const int n = n0w + g * 16 + j;
        const bool valid = (n < N_NODES);
        const size_t nn = valid ? (size_t)n : 0;

        frag8 bfr[8];
        const float* nrow = node_emb + nn * D_NODE;
#pragma unroll
        for (int kc = 0; kc < 4; ++kc) {
            float4 a = *(const float4*)&nrow[kc * 32 + q * 8];
            float4 c = *(const float4*)&nrow[kc * 32 + q * 8 + 4];
            bfr[kc] = pack8(a, c);
        }
        const float* mrow = mean + nn * D_MSG;
#pragma unroll
        for (int kc = 0; kc < 4; ++kc) {
            float4 a = *(const float4*)&mrow[kc * 32 + q * 8];
            float4 c = *(const float4*)&mrow[kc * 32 + q * 8 + 4];
            bfr[4 + kc] = pack8(a, c);
        }

        facc acc[8];
#pragma unroll
        for (int mt = 0; mt < 8; ++mt) { facc z = {0.f, 0.f, 0.f, 0.f}; acc[mt] = z; }

#pragma unroll
        for (int mt = 0; mt < 8; ++mt) {
            const unsigned short* wrow = &sW[(mt * 16 + j) * K2];
            const int rs = j & 7;
#pragma unroll
            for (int kc = 0; kc < 8; ++kc) {
                frag8 a = *(const frag8*)&wrow[((kc * 4 + q) ^ rs) * 8];
                acc[mt] = __builtin_amdgcn_mfma_f32_16x16x32_bf16(a, bfr[kc], acc[mt], 0, 0, 0);
            }
        }

        if (valid) {
            float* orow = out + (size_t)n * D_OUT;
#pragma unroll
            for (int mt = 0; mt < 8; ++mt)
#pragma unroll
                for (int r = 0; r < 4; ++r)
                    orow[mt * 16 + q * 4 + r] = fmaxf(acc[mt][r] + bias[mt * 4 + r], 0.f);
        }
    }
}

extern "C" void kernel_launch(void* const* d_in, const int* in_sizes, int n_in,
                              void* d_out, int out_size, void* d_ws, size_t ws_size,
                              hipStream_t stream) {
    const float* node_emb = (const float*)d_in[0];
    const int*   edge_idx = (const int*)d_in[1];
    const float* edge_emb = (const float*)d_in[2];
    const float* W_msg    = (const float*)d_in[3];
    const float* b_msg    = (const float*)d_in[4];
    const float* W_upd    = (const float*)d_in[5];
    const float* b_upd    = (const float*)d_in[6];
    float* out = (float*)d_out;

    const int* src = edge_idx;
    const int* dst = edge_idx + N_EDGES;

    char* W = (char*)d_ws;

    if (ws_size >= 321315200ULL) {
        // ---- FAST PATH ----
        float* mean  = (float*)(W + 0);                           // 51,200,000
        int* cnt     = (int*)(W + 51200000);                      //    400,000
        int* cursor  = (int*)(W + 51600000);                      //    400,000
        int* base    = (int*)(W + 52000000);                      //    400,000
        int* part    = (int*)(W + 52400000);                      //        512
        int* srcS    = (int*)(W + 52400512);                      //  6,400,000
        int* dstS    = (int*)(W + 58800512);                      //  6,400,000
        unsigned short* WtM   = (unsigned short*)(W + 65200512);  //     49,152
        unsigned short* WtU   = (unsigned short*)(W + 65249664);  //     65,536
        unsigned short* nodeB = (unsigned short*)(W + 65315200);  // 25,600,000
        unsigned short* edgeB = (unsigned short*)(W + 90915200);  // 204,800,000
        float* spill = (float*)(W + 295715200);                   //  25,600,000

        // zero only cnt + cursor (mean fully overwritten; spill slots
        // read only if written this call)
        hipMemsetAsync(W + 51200000, 0, 800000, stream);

        prep_all_kernel<<<2048, 256, 0, stream>>>(W_msg, W_upd, node_emb, dst,
                                                  WtM, WtU, (unsigned int*)nodeB, cnt);
        scan_blocks<<<NSB, 1024, 0, stream>>>(cnt, base, part);
        scan_partials<<<1, 128, 0, stream>>>(part);
        scan_add<<<NSB, 1024, 0, stream>>>(base, part);
        scatter2_kernel<<<2048, 256, 0, stream>>>(dst, src, edge_emb, base, cursor,
                                                  srcS, dstS, edgeB);
        msg_fused_kernel<<<2048, 256, 0, stream>>>(nodeB, srcS, dstS, edgeB,
                                                   WtM, b_msg, base, cnt, mean, spill);
        cleanup_kernel<<<25000, 256, 0, stream>>>(dstS, base, cnt, spill, mean);
        node_gemm_kernel<<<391, 256, 0, stream>>>(nodeB, mean, WtU, b_upd, out);
    } else {
        // ---- FALLBACK (round-3 layout & kernels) ----
        float* mean  = (float*)W;                               // 51,200,000
        int* cnt     = (int*)(W + 51200000);
        int* cursor  = (int*)(W + 51600000);
        int* base    = (int*)(W + 52000000);
        int* part    = (int*)(W + 52400000);
        int* perm    = (int*)(W + 52400512);
        int* dstS    = (int*)(W + 58800512);
        int* srcS    = (int*)(W + 65200512);
        unsigned short* WtM = (unsigned short*)(W + 71600512);
        unsigned short* WtU = (unsigned short*)(W + 71649664);

        hipMemsetAsync(d_ws, 0, 52000000, stream);

        prep_w_kernel<<<224, 256, 0, stream>>>(W_msg, W_upd, WtM, WtU);
        hist_kernel<<<1024, 256, 0, stream>>>(dst, cnt);
        scan_blocks<<<NSB, 1024, 0, stream>>>(cnt, base, part);
        scan_partials<<<1, 128, 0, stream>>>(part);
        scan_add<<<NSB, 1024, 0, stream>>>(base, part);
        scatter_kernel<<<1024, 256, 0, stream>>>(dst, src, base, cursor, perm, srcS, dstS);
        msg_agg_kernel_fb<<<6250, 256, 0, stream>>>(node_emb, src, edge_emb, WtM,
                                                    b_msg, perm, dstS, cnt, mean);
        node_kernel_fb<<<391, 256, 0, stream>>>(node_emb, mean, WtU, b_upd, out);
    }
}

// Round 9
// 611.135 us; speedup vs baseline: 1.1706x; 1.1706x over previous
//
#include <hip/hip_runtime.h>
#include <hip/hip_bf16.h>

#define N_NODES 100000
#define N_EDGES 1600000
#define D_NODE 128
#define D_EDGE 64
#define D_MSG 128
#define K1 192   // NODE_DIM + EDGE_DIM
#define K2 256   // NODE_DIM + MSG_DIM
#define D_OUT 128
#define NSB 98   // scan blocks: ceil(100000/1024)
#define TILE 64
#define NT (N_EDGES / TILE)   // 25000 exact

using frag8 = __attribute__((ext_vector_type(8))) short;   // 8 bf16 (4 VGPRs)
using facc  = __attribute__((ext_vector_type(4))) float;   // 4 f32 acc

static __device__ __forceinline__ unsigned short f2bf(float f) {
    unsigned int u = __float_as_uint(f);
    u = u + 0x7fffu + ((u >> 16) & 1u);   // RNE
    return (unsigned short)(u >> 16);
}
static __device__ __forceinline__ float bflo(unsigned int u) { return __uint_as_float(u << 16); }
static __device__ __forceinline__ float bfhi(unsigned int u) { return __uint_as_float(u & 0xffff0000u); }

union F8 { unsigned short s[8]; frag8 f; uint4 u4; };

static __device__ __forceinline__ frag8 pack8(float4 a, float4 b) {
    F8 u;
    u.s[0] = f2bf(a.x); u.s[1] = f2bf(a.y); u.s[2] = f2bf(a.z); u.s[3] = f2bf(a.w);
    u.s[4] = f2bf(b.x); u.s[5] = f2bf(b.y); u.s[6] = f2bf(b.z); u.s[7] = f2bf(b.w);
    return u.f;
}

// ---------------------------------------------------------------------------
// prep_all: W transpose->bf16, node_emb->bf16, dst histogram. One launch.
// ---------------------------------------------------------------------------
__global__ void prep_all_kernel(const float* __restrict__ Wm, const float* __restrict__ Wu,
                                const float* __restrict__ node_emb, const int* __restrict__ dst,
                                unsigned short* __restrict__ WtM, unsigned short* __restrict__ WtU,
                                unsigned int* __restrict__ nodeB32, int* __restrict__ cnt) {
    int idx0 = blockIdx.x * blockDim.x + threadIdx.x;
    int stride = gridDim.x * blockDim.x;
    for (int idx = idx0; idx < 128 * K1; idx += stride) {
        int o = idx / K1, k = idx - o * K1;
        WtM[idx] = f2bf(Wm[k * D_MSG + o]);
    }
    for (int idx = idx0; idx < 128 * K2; idx += stride) {
        int o = idx >> 8, k = idx & 255;
        WtU[idx] = f2bf(Wu[k * D_OUT + o]);
    }
    const int total = N_NODES * 64;   // u32 pairs
    for (int i = idx0; i < total; i += stride) {
        float2 v = *(const float2*)&node_emb[(size_t)i * 2];
        nodeB32[i] = (unsigned)f2bf(v.x) | ((unsigned)f2bf(v.y) << 16);
    }
    for (int e = idx0; e < N_EDGES; e += stride) {
        int d = min(max(dst[e], 0), N_NODES - 1);
        atomicAdd(&cnt[d], 1);
    }
}

__global__ __launch_bounds__(1024) void scan_blocks(const int* __restrict__ cnt,
                                                    int* __restrict__ base,
                                                    int* __restrict__ part) {
    __shared__ int sh[1024];
    int i = blockIdx.x * 1024 + threadIdx.x;
    int c = (i < N_NODES) ? cnt[i] : 0;
    sh[threadIdx.x] = c;
    __syncthreads();
    for (int s = 1; s < 1024; s <<= 1) {
        int t = (threadIdx.x >= s) ? sh[threadIdx.x - s] : 0;
        __syncthreads();
        sh[threadIdx.x] += t;
        __syncthreads();
    }
    if (i < N_NODES) base[i] = sh[threadIdx.x] - c;   // exclusive within block
    if (threadIdx.x == 1023) part[blockIdx.x] = sh[1023];
}

__global__ __launch_bounds__(128) void scan_partials(int* __restrict__ part) {
    __shared__ int sh[128];
    int i = threadIdx.x;
    int c = (i < NSB) ? part[i] : 0;
    sh[i] = c;
    __syncthreads();
    for (int s = 1; s < 128; s <<= 1) {
        int t = (i >= s) ? sh[i - s] : 0;
        __syncthreads();
        sh[i] += t;
        __syncthreads();
    }
    if (i < NSB) part[i] = sh[i] - c;   // exclusive
}

__global__ __launch_bounds__(1024) void scan_add(int* __restrict__ base, const int* __restrict__ part) {
    int i = blockIdx.x * 1024 + threadIdx.x;
    if (i < N_NODES) base[i] += part[blockIdx.x];
}

// bins edges by dst; emits perm (orig idx), srcS (src in sorted order), dstS
__global__ void scatter_kernel(const int* __restrict__ dst, const int* __restrict__ src,
                               const int* __restrict__ base, int* __restrict__ cursor,
                               int* __restrict__ perm, int* __restrict__ srcS,
                               int* __restrict__ dstS) {
    int idx0 = blockIdx.x * blockDim.x + threadIdx.x;
    int stride = gridDim.x * blockDim.x;
    for (int e = idx0; e < N_EDGES; e += stride) {
        int d = min(max(dst[e], 0), N_NODES - 1);
        int pos = base[d] + atomicAdd(&cursor[d], 1);
        perm[pos] = e;
        srcS[pos] = src[e];
        dstS[pos] = d;
    }
}

// ---------------------------------------------------------------------------
// FUSED Phase A (round-6 structure + bf16 mean + spill/cleanup):
// per 64-edge tile: msg GEMM (W in regs, inputs staged in XOR-swizzled LDS)
// -> msg tile in LDS -> in-block per-node mean. Interior nodes: direct bf16
// mean row write. Non-interior: plain f32 spill row (NO atomics).
// ---------------------------------------------------------------------------
__global__ __launch_bounds__(256, 4) void msg_fused_kernel(
    const unsigned short* __restrict__ nodeB, const int* __restrict__ srcS,
    const int* __restrict__ perm, const int* __restrict__ dstS,
    const float* __restrict__ edge_emb, const unsigned short* __restrict__ WtM,
    const float* __restrict__ b_msg, const int* __restrict__ base,
    const int* __restrict__ cnt, unsigned int* __restrict__ meanB32,
    float* __restrict__ spill)
{
    __shared__ unsigned short sIn[TILE][192];    // 24576 B; 16B chunks XOR row&7
    __shared__ unsigned short sMsg[TILE][128];   // 16384 B; 8B chunks XOR row&7

    const int lane = threadIdx.x & 63;
    const int wav  = threadIdx.x >> 6;
    const int j = lane & 15;
    const int q = lane >> 4;

    // W slice (out rows 32*wav .. 32*wav+31) in registers
    frag8 wfr[2][6];
#pragma unroll
    for (int m2 = 0; m2 < 2; ++m2) {
        const unsigned short* wrow = WtM + ((wav * 2 + m2) * 16 + j) * K1;
#pragma unroll
        for (int kc = 0; kc < 6; ++kc)
            wfr[m2][kc] = *(const frag8*)&wrow[(kc * 4 + q) * 8];
    }
    float bias[2][4];
#pragma unroll
    for (int m2 = 0; m2 < 2; ++m2)
#pragma unroll
        for (int r = 0; r < 4; ++r) bias[m2][r] = b_msg[(wav * 2 + m2) * 16 + q * 4 + r];

    // staging role: thread t covers edge row eL = t>>2, quarter qt = t&3
    const int eL = threadIdx.x >> 2;
    const int qt = threadIdx.x & 3;
    const int swz = eL & 7;

    uint4  nst[4];    // node part: 64B bf16
    float4 est[4];    // edge part: 64B f32 (random gather via perm)

    const int t0 = blockIdx.x;

    // prologue: issue loads for tile t0
    {
        const int e = t0 * TILE + eL;
        const int sp = min(max(srcS[e], 0), N_NODES - 1);
        const unsigned short* nrow = nodeB + (size_t)sp * D_NODE + qt * 32;
#pragma unroll
        for (int i = 0; i < 4; ++i) nst[i] = *(const uint4*)&nrow[i * 8];
        const float* erow = edge_emb + (size_t)perm[e] * D_EDGE + qt * 16;
#pragma unroll
        for (int i = 0; i < 4; ++i) est[i] = *(const float4*)&erow[i * 4];
    }

#pragma unroll 1
    for (int t = t0; t < NT; t += gridDim.x) {
        const int e0 = t * TILE;

        __syncthreads();   // (a) prior GEMM + reduction done; sIn free

        // write staged tile into sIn (XOR-swizzled 16B chunks)
        {
            unsigned short* drow = &sIn[eL][0];
#pragma unroll
            for (int i = 0; i < 4; ++i)
                *(uint4*)&drow[((4 * qt + i) ^ swz) * 8] = nst[i];
#pragma unroll
            for (int h = 0; h < 2; ++h) {
                F8 u;
                u.f = pack8(est[h * 2], est[h * 2 + 1]);
                *(uint4*)&drow[((16 + 2 * qt + h) ^ swz) * 8] = u.u4;
            }
        }
        __syncthreads();   // (b) sIn ready

        // issue next tile's loads early (latency hides under compute)
        const int tn = t + gridDim.x;
        if (tn < NT) {
            const int e = tn * TILE + eL;
            const int sp = min(max(srcS[e], 0), N_NODES - 1);
            const unsigned short* nrow = nodeB + (size_t)sp * D_NODE + qt * 32;
#pragma unroll
            for (int i = 0; i < 4; ++i) nst[i] = *(const uint4*)&nrow[i * 8];
            const float* erow = edge_emb + (size_t)perm[e] * D_EDGE + qt * 16;
#pragma unroll
            for (int i = 0; i < 4; ++i) est[i] = *(const float4*)&erow[i * 4];
        }

        // GEMM: wave computes outs 32*wav..+31 for all 64 edges
        facc acc[2][4];
#pragma unroll
        for (int m2 = 0; m2 < 2; ++m2)
#pragma unroll
            for (int eg = 0; eg < 4; ++eg) { facc z = {0.f,0.f,0.f,0.f}; acc[m2][eg] = z; }

        const int rsw = j & 7;
#pragma unroll
        for (int eg = 0; eg < 4; ++eg) {
            const unsigned short* irow = &sIn[eg * 16 + j][0];
#pragma unroll
            for (int kc = 0; kc < 6; ++kc) {
                frag8 b = *(const frag8*)&irow[((4 * kc + q) ^ rsw) * 8];
                acc[0][eg] = __builtin_amdgcn_mfma_f32_16x16x32_bf16(wfr[0][kc], b, acc[0][eg], 0, 0, 0);
                acc[1][eg] = __builtin_amdgcn_mfma_f32_16x16x32_bf16(wfr[1][kc], b, acc[1][eg], 0, 0, 0);
            }
        }

        // epilogue: bias+relu+cvt bf16 -> sMsg (8B chunks XOR row&7)
#pragma unroll
        for (int eg = 0; eg < 4; ++eg) {
            unsigned short* mrow = &sMsg[eg * 16 + j][0];
#pragma unroll
            for (int m2 = 0; m2 < 2; ++m2) {
                float v0 = fmaxf(acc[m2][eg][0] + bias[m2][0], 0.f);
                float v1 = fmaxf(acc[m2][eg][1] + bias[m2][1], 0.f);
                float v2 = fmaxf(acc[m2][eg][2] + bias[m2][2], 0.f);
                float v3 = fmaxf(acc[m2][eg][3] + bias[m2][3], 0.f);
                uint2 w;
                w.x = (unsigned)f2bf(v0) | ((unsigned)f2bf(v1) << 16);
                w.y = (unsigned)f2bf(v2) | ((unsigned)f2bf(v3) << 16);
                int c64 = wav * 8 + m2 * 4 + q;        // u64 index 0..31
                *(uint2*)&mrow[(c64 ^ rsw) * 4] = w;
            }
        }
        __syncthreads();   // (c) sMsg ready

        // in-block mean finish: wave handles nodes d_lo+wav, +4, ...
        const int d_lo = dstS[e0];
        const int d_hi = dstS[e0 + TILE - 1];
        for (int n = d_lo + wav; n <= d_hi; n += 4) {
            const int b = base[n];
            const int c = cnt[n];
            const int lo = max(b - e0, 0);
            const int hi = min(b + c - e0, TILE);
            float s0 = 0.f, s1 = 0.f;
            for (int r = lo; r < hi; ++r) {
                const unsigned* mr = (const unsigned*)&sMsg[r][0];
                unsigned u = mr[(((lane >> 1) ^ (r & 7)) << 1) | (lane & 1)];
                s0 += bflo(u); s1 += bfhi(u);
            }
            const float inv = 1.0f / fmaxf((float)c, 1.0f);
            s0 *= inv; s1 *= inv;
            if (b >= e0 && b + c <= e0 + TILE) {
                // interior: exclusive owner, direct bf16 mean row write (256B/wave)
                meanB32[(size_t)n * 64 + lane] =
                    (unsigned)f2bf(s0) | ((unsigned)f2bf(s1) << 16);
            } else {
                // non-interior: deterministic f32 spill slot (NO atomics)
                int slot = (n == d_lo) ? 0 : 1;
                *(float2*)(spill + ((size_t)(t * 2 + slot)) * D_MSG + lane * 2) =
                    make_float2(s0, s1);
            }
        }
    }
}

// ---------------------------------------------------------------------------
// cleanup: finish boundary nodes (sum their per-tile spill rows) and write
// zero rows for degree-0 nodes. Interior nodes were written by msg_fused.
// ---------------------------------------------------------------------------
__global__ __launch_bounds__(256) void cleanup_kernel(
    const int* __restrict__ dstS, const int* __restrict__ base,
    const int* __restrict__ cnt, const float* __restrict__ spill,
    unsigned int* __restrict__ meanB32)
{
    const int wav = threadIdx.x >> 6;
    const int lane = threadIdx.x & 63;
    const int n = blockIdx.x * 4 + wav;
    const int c = cnt[n];
    float s0 = 0.f, s1 = 0.f;
    if (c > 0) {
        const int b = base[n];
        const int t0 = b >> 6, t1 = (b + c - 1) >> 6;
        if (t0 == t1) return;   // interior: already written by msg_fused
        for (int t = t0; t <= t1; ++t) {
            const int slot = (dstS[t * TILE] == n) ? 0 : 1;
            const float* sp = spill + ((size_t)(t * 2 + slot)) * D_MSG + lane * 2;
            s0 += sp[0]; s1 += sp[1];
        }
    }
    meanB32[(size_t)n * 64 + lane] = (unsigned)f2bf(s0) | ((unsigned)f2bf(s1) << 16);
}

// ---------------------------------------------------------------------------
// Phase C: node GEMM, all-bf16 fragment loads (nodeB + meanB).
// ---------------------------------------------------------------------------
__global__ __launch_bounds__(256) void node_gemm_kernel(
    const unsigned short* __restrict__ nodeB, const unsigned short* __restrict__ meanB,
    const unsigned short* __restrict__ WtU, const float* __restrict__ b_upd,
    float* __restrict__ out)
{
    __shared__ unsigned short sW[128 * K2];   // 65536 B

    for (int idx = threadIdx.x; idx < 128 * 32; idx += 256) {
        int o = idx >> 5, ch = idx & 31;
        *(uint4*)&sW[o * K2 + (ch ^ (o & 7)) * 8] = *(const uint4*)&WtU[o * K2 + ch * 8];
    }

    const int lane = threadIdx.x & 63;
    const int wav  = threadIdx.x >> 6;
    const int j = lane & 15;
    const int q = lane >> 4;
    const int rs = j & 7;

    float bias[32];
#pragma unroll
    for (int mt = 0; mt < 8; ++mt)
#pragma unroll
        for (int r = 0; r < 4; ++r) bias[mt * 4 + r] = b_upd[mt * 16 + q * 4 + r];
    __syncthreads();

    const int n0w = blockIdx.x * 256 + wav * 64;

#pragma unroll 1
    for (int g = 0; g < 4; ++g) {
        const int n = n0w + g * 16 + j;
        const bool valid = (n < N_NODES);
        const size_t nn = valid ? (size_t)n : 0;

        frag8 bfr[8];
        const unsigned short* nrow = nodeB + nn * D_NODE;
#pragma unroll
        for (int kc = 0; kc < 4; ++kc)
            bfr[kc] = *(const frag8*)&nrow[kc * 32 + q * 8];
        const unsigned short* mrow = meanB + nn * D_MSG;
#pragma unroll
        for (int kc = 0; kc < 4; ++kc)
            bfr[4 + kc] = *(const frag8*)&mrow[kc * 32 + q * 8];

        facc acc[8];
#pragma unroll
        for (int mt = 0; mt < 8; ++mt) { facc z = {0.f, 0.f, 0.f, 0.f}; acc[mt] = z; }

#pragma unroll
        for (int mt = 0; mt < 8; ++mt) {
            const unsigned short* wrow = &sW[(mt * 16 + j) * K2];
#pragma unroll
            for (int kc = 0; kc < 8; ++kc) {
                frag8 a = *(const frag8*)&wrow[((kc * 4 + q) ^ rs) * 8];
                acc[mt] = __builtin_amdgcn_mfma_f32_16x16x32_bf16(a, bfr[kc], acc[mt], 0, 0, 0);
            }
        }

        if (valid) {
            float* orow = out + (size_t)n * D_OUT;
#pragma unroll
            for (int mt = 0; mt < 8; ++mt)
#pragma unroll
                for (int r = 0; r < 4; ++r)
                    orow[mt * 16 + q * 4 + r] = fmaxf(acc[mt][r] + bias[mt * 4 + r], 0.f);
        }
    }
}

// ===========================================================================
// FALLBACK PATH (round-3): fused msg+aggregate if ws too small.
// ===========================================================================
__global__ void prep_w_kernel(const float* __restrict__ Wm, const float* __restrict__ Wu,
                              unsigned short* __restrict__ WtM, unsigned short* __restrict__ WtU) {
    int idx0 = blockIdx.x * blockDim.x + threadIdx.x;
    int stride = gridDim.x * blockDim.x;
    for (int idx = idx0; idx < 128 * K1; idx += stride) {
        int o = idx / K1, k = idx - o * K1;
        WtM[idx] = f2bf(Wm[k * D_MSG + o]);
    }
    for (int idx = idx0; idx < 128 * K2; idx += stride) {
        int o = idx >> 8, k = idx & 255;
        WtU[idx] = f2bf(Wu[k * D_OUT + o]);
    }
}

__global__ void hist_kernel(const int* __restrict__ dst, int* __restrict__ cnt) {
    int idx0 = blockIdx.x * blockDim.x + threadIdx.x;
    int stride = gridDim.x * blockDim.x;
    for (int e = idx0; e < N_EDGES; e += stride) {
        int d = min(max(dst[e], 0), N_NODES - 1);
        atomicAdd(&cnt[d], 1);
    }
}

__global__ __launch_bounds__(256) void msg_agg_kernel_fb(
    const float* __restrict__ node_emb, const int* __restrict__ src,
    const float* __restrict__ edge_emb, const unsigned short* __restrict__ WtM,
    const float* __restrict__ b_msg, const int* __restrict__ perm,
    const int* __restrict__ dstS, const int* __restrict__ cnt,
    float* __restrict__ mean)
{
    __shared__ unsigned short sW[128 * K1];

    for (int idx = threadIdx.x; idx < 128 * 24; idx += 256) {
        int o = idx / 24, ch = idx % 24;
        *(uint4*)&sW[o * K1 + (ch ^ (o & 7)) * 8] = *(const uint4*)&WtM[o * K1 + ch * 8];
    }

    const int lane = threadIdx.x & 63;
    const int wav  = threadIdx.x >> 6;
    const int j = lane & 15;
    const int q = lane >> 4;

    float bias[32];
#pragma unroll
    for (int mt = 0; mt < 8; ++mt)
#pragma unroll
        for (int r = 0; r < 4; ++r) bias[mt * 4 + r] = b_msg[mt * 16 + q * 4 + r];
    __syncthreads();

    const int e0w = blockIdx.x * 256 + wav * 64;
    float carry[32];
    int carry_d = -1;

#pragma unroll 1
    for (int g = 0; g < 4; ++g) {
        const int e = e0w + g * 16 + j;
        const int p = perm[e];
        const int d = dstS[e];
        const int sp = min(max(src[p], 0), N_NODES - 1);
        const float invc = 1.0f / (float)cnt[d];

        frag8 bfr[6];
        const float* nrow = node_emb + (size_t)sp * D_NODE;
#pragma unroll
        for (int kc = 0; kc < 4; ++kc) {
            float4 a = *(const float4*)&nrow[kc * 32 + q * 8];
            float4 c = *(const float4*)&nrow[kc * 32 + q * 8 + 4];
            bfr[kc] = pack8(a, c);
        }
        const float* erow = edge_emb + (size_t)p * D_EDGE;
#pragma unroll
        for (int kc = 0; kc < 2; ++kc) {
            float4 a = *(const float4*)&erow[kc * 32 + q * 8];
            float4 c = *(const float4*)&erow[kc * 32 + q * 8 + 4];
            bfr[4 + kc] = pack8(a, c);
        }

        facc acc[8];
#pragma unroll
        for (int mt = 0; mt < 8; ++mt) { facc z = {0.f, 0.f, 0.f, 0.f}; acc[mt] = z; }

#pragma unroll
        for (int mt = 0; mt < 8; ++mt) {
            const unsigned short* wrow = &sW[(mt * 16 + j) * K1];
            const int rs = j & 7;
#pragma unroll
            for (int kc = 0; kc < 6; ++kc) {
                frag8 a = *(const frag8*)&wrow[((kc * 4 + q) ^ rs) * 8];
                acc[mt] = __builtin_amdgcn_mfma_f32_16x16x32_bf16(a, bfr[kc], acc[mt], 0, 0, 0);
            }
        }

        float v[32];
#pragma unroll
        for (int mt = 0; mt < 8; ++mt)
#pragma unroll
            for (int r = 0; r < 4; ++r) {
                float t = acc[mt][r] + bias[mt * 4 + r];
                v[mt * 4 + r] = fmaxf(t, 0.f) * invc;
            }

        int dprev = __shfl_up(d, 1, 16);
        int head = (j == 0 || d != dprev) ? 1 : 0;
        int seg = head;
#pragma unroll
        for (int s = 1; s < 16; s <<= 1) { int t = __shfl_up(seg, s, 16); if (j >= s) seg += t; }
        int sg1 = __shfl_up(seg, 1, 16);
        int sg2 = __shfl_up(seg, 2, 16);
        int sg4 = __shfl_up(seg, 4, 16);
        int sg8 = __shfl_up(seg, 8, 16);
        bool ok1 = (j >= 1) && (sg1 == seg);
        bool ok2 = (j >= 2) && (sg2 == seg);
        bool ok4 = (j >= 4) && (sg4 == seg);
        bool ok8 = (j >= 8) && (sg8 == seg);

#pragma unroll
        for (int i = 0; i < 32; ++i) { float t = __shfl_up(v[i], 1, 16); if (ok1) v[i] += t; }
#pragma unroll
        for (int i = 0; i < 32; ++i) { float t = __shfl_up(v[i], 2, 16); if (ok2) v[i] += t; }
#pragma unroll
        for (int i = 0; i < 32; ++i) { float t = __shfl_up(v[i], 4, 16); if (ok4) v[i] += t; }
#pragma unroll
        for (int i = 0; i < 32; ++i) { float t = __shfl_up(v[i], 8, 16); if (ok8) v[i] += t; }

        int d0 = __shfl(d, 0, 16);
        if (g > 0) {
            if (d0 != carry_d) {
                if (j == 0) {
                    float* mrow = mean + (size_t)carry_d * D_MSG;
#pragma unroll
                    for (int mt = 0; mt < 8; ++mt)
#pragma unroll
                        for (int r = 0; r < 4; ++r)
                            atomicAdd(&mrow[mt * 16 + q * 4 + r], carry[mt * 4 + r]);
                }
            } else if (seg == 1) {
#pragma unroll
                for (int i = 0; i < 32; ++i) v[i] += carry[i];
            }
        }

#pragma unroll
        for (int i = 0; i < 32; ++i) carry[i] = __shfl(v[i], 15, 16);
        carry_d = __shfl(d, 15, 16);

        int dnext = __shfl_down(d, 1, 16);
        bool tail = (j < 15) ? (dnext != d) : (g == 3);
        if (tail) {
            float* mrow = mean + (size_t)d * D_MSG;
#pragma unroll
            for (int mt = 0; mt < 8; ++mt)
#pragma unroll
                for (int r = 0; r < 4; ++r)
                    atomicAdd(&mrow[mt * 16 + q * 4 + r], v[mt * 4 + r]);
        }
    }
}

__global__ __launch_bounds__(256) void node_kernel_fb(
    const float* __restrict__ node_emb, const float* __restrict__ mean,
    const unsigned short* __restrict__ WtU, const float* __restrict__ b_upd,
    float* __restrict__ out)
{
    __shared__ unsigned short sW[128 * K2];

    for (int idx = threadIdx.x; idx < 128 * 32; idx += 256) {
        int o = idx >> 5, ch = idx & 31;
        *(uint4*)&sW[o * K2 + (ch ^ (o & 7)) * 8] = *(const uint4*)&WtU[o * K2 + ch * 8];
    }

    const int lane = threadIdx.x & 63;
    const int wav  = threadIdx.x >> 6;
    const int j = lane & 15;
    const int q = lane >> 4;

    float bias[32];
#pragma unroll
    for (int mt = 0; mt < 8; ++mt)
#pragma unroll
        for (int r = 0; r < 4; ++r) bias[mt * 4 + r] = b_upd[mt * 16 + q * 4 + r];
    __syncthreads();

    const int n0w = blockIdx.x * 256 + wav * 64;

#pragma unroll 1
    for (int g = 0; g < 4; ++g) {
        const int n = n0w + g * 16 + j;
        const bool valid = (n < N_NODES);
        const size_t nn = valid ? (size_t)n : 0;

        frag8 bfr[8];
        const float* nrow = node_emb + nn * D_NODE;
#pragma unroll
        for (int kc = 0; kc < 4; ++kc) {
            float4 a = *(const float4*)&nrow[kc * 32 + q * 8];
            float4 c = *(const float4*)&nrow[kc * 32 + q * 8 + 4];
            bfr[kc] = pack8(a, c);
        }
        const float* mrow = mean + nn * D_MSG;
#pragma unroll
        for (int kc = 0; kc < 4; ++kc) {
            float4 a = *(const float4*)&mrow[kc * 32 + q * 8];
            float4 c = *(const float4*)&mrow[kc * 32 + q * 8 + 4];
            bfr[4 + kc] = pack8(a, c);
        }

        facc acc[8];
#pragma unroll
        for (int mt = 0; mt < 8; ++mt) { facc z = {0.f, 0.f, 0.f, 0.f}; acc[mt] = z; }

#pragma unroll
        for (int mt = 0; mt < 8; ++mt) {
            const unsigned short* wrow = &sW[(mt * 16 + j) * K2];
            const int rs = j & 7;
#pragma unroll
            for (int kc = 0; kc < 8; ++kc) {
                frag8 a = *(const frag8*)&wrow[((kc * 4 + q) ^ rs) * 8];
                acc[mt] = __builtin_amdgcn_mfma_f32_16x16x32_bf16(a, bfr[kc], acc[mt], 0, 0, 0);
            }
        }

        if (valid) {
            float* orow = out + (size_t)n * D_OUT;
#pragma unroll
            for (int mt = 0; mt < 8; ++mt)
#pragma unroll
                for (int r = 0; r < 4; ++r)
                    orow[mt * 16 + q * 4 + r] = fmaxf(acc[mt][r] + bias[mt * 4 + r], 0.f);
        }
    }
}

extern "C" void kernel_launch(void* const* d_in, const int* in_sizes, int n_in,
                              void* d_out, int out_size, void* d_ws, size_t ws_size,
                              hipStream_t stream) {
    const float* node_emb = (const float*)d_in[0];
    const int*   edge_idx = (const int*)d_in[1];
    const float* edge_emb = (const float*)d_in[2];
    const float* W_msg    = (const float*)d_in[3];
    const float* b_msg    = (const float*)d_in[4];
    const float* W_upd    = (const float*)d_in[5];
    const float* b_upd    = (const float*)d_in[6];
    float* out = (float*)d_out;

    const int* src = edge_idx;
    const int* dst = edge_idx + N_EDGES;

    char* W = (char*)d_ws;

    if (ws_size >= 98000000ULL) {
        // ---- FAST PATH ----
        unsigned short* meanB = (unsigned short*)(W + 0);         // 25,600,000
        int* cnt     = (int*)(W + 25600000);                      //    400,000
        int* cursor  = (int*)(W + 26000000);                      //    400,000
        int* base    = (int*)(W + 26400000);                      //    400,000
        int* part    = (int*)(W + 26800000);                      //        512
        int* perm    = (int*)(W + 26800512);                      //  6,400,000
        int* srcS    = (int*)(W + 33200512);                      //  6,400,000
        int* dstS    = (int*)(W + 39600512);                      //  6,400,000
        unsigned short* WtM   = (unsigned short*)(W + 46000512);  //     49,152
        unsigned short* WtU   = (unsigned short*)(W + 46049664);  //     65,536
        unsigned short* nodeB = (unsigned short*)(W + 46115200);  // 25,600,000
        float* spill = (float*)(W + 71715200);                    //  25,600,000

        // zero only cnt + cursor
        hipMemsetAsync(W + 25600000, 0, 800000, stream);

        prep_all_kernel<<<2048, 256, 0, stream>>>(W_msg, W_upd, node_emb, dst,
                                                  WtM, WtU, (unsigned int*)nodeB, cnt);
        scan_blocks<<<NSB, 1024, 0, stream>>>(cnt, base, part);
        scan_partials<<<1, 128, 0, stream>>>(part);
        scan_add<<<NSB, 1024, 0, stream>>>(base, part);
        scatter_kernel<<<1024, 256, 0, stream>>>(dst, src, base, cursor, perm, srcS, dstS);
        msg_fused_kernel<<<2048, 256, 0, stream>>>(nodeB, srcS, perm, dstS, edge_emb,
                                                   WtM, b_msg, base, cnt,
                                                   (unsigned int*)meanB, spill);
        cleanup_kernel<<<25000, 256, 0, stream>>>(dstS, base, cnt, spill,
                                                  (unsigned int*)meanB);
        node_gemm_kernel<<<391, 256, 0, stream>>>(nodeB, meanB, WtU, b_upd, out);
    } else {
        // ---- FALLBACK (round-3 layout & kernels) ----
        float* mean  = (float*)W;                               // 51,200,000
        int* cnt     = (int*)(W + 51200000);
        int* cursor  = (int*)(W + 51600000);
        int* base    = (int*)(W + 52000000);
        int* part    = (int*)(W + 52400000);
        int* perm    = (int*)(W + 52400512);
        int* dstS    = (int*)(W + 58800512);
        int* srcS    = (int*)(W + 65200512);
        unsigned short* WtM = (unsigned short*)(W + 71600512);
        unsigned short* WtU = (unsigned short*)(W + 71649664);

        hipMemsetAsync(d_ws, 0, 52000000, stream);

        prep_w_kernel<<<224, 256, 0, stream>>>(W_msg, W_upd, WtM, WtU);
        hist_kernel<<<1024, 256, 0, stream>>>(dst, cnt);
        scan_blocks<<<NSB, 1024, 0, stream>>>(cnt, base, part);
        scan_partials<<<1, 128, 0, stream>>>(part);
        scan_add<<<NSB, 1024, 0, stream>>>(base, part);
        scatter_kernel<<<1024, 256, 0, stream>>>(dst, src, base, cursor, perm, srcS, dstS);
        msg_agg_kernel_fb<<<6250, 256, 0, stream>>>(node_emb, src, edge_emb, WtM,
                                                    b_msg, perm, dstS, cnt, mean);
        node_kernel_fb<<<391, 256, 0, stream>>>(node_emb, mean, WtU, b_upd, out);
    }
}